// Round 1
// baseline (1652.477 us; speedup 1.0000x reference)
//
#include <hip/hip_runtime.h>

#define N_TRIALS  8
#define T_MS      2500
#define N_NEURONS 16000
#define N_SAMPLES 50
#define K_MAX     160
#define N_BINS    20
#define SYNC_COST 10.0f
#define EPS_F     1e-7f

// np.round(np.logspace(-3, 0, 20) * 1000)
__device__ const int BIN_SIZES[N_BINS] = {1, 1, 2, 3, 4, 6, 9, 13, 18, 26,
                                          38, 55, 78, 113, 162, 234, 336, 483, 695, 1000};

// Kernel 1: sel[s][t] = sum_{k < count_s} spikes[trial_s][t][idx[s][k]]
// One wave per t; lanes stride over k. Block = 4 waves, covers 100 t's.
__global__ __launch_bounds__(256) void sel_kernel(
    const float* __restrict__ spikes,
    const int*   __restrict__ trials,
    const int*   __restrict__ idx,
    const int*   __restrict__ counts,
    float*       __restrict__ sel)
{
    const int s      = blockIdx.x;
    const int t_base = blockIdx.y * 100;
    const int tid    = threadIdx.x;
    const int lane   = tid & 63;
    const int wave   = tid >> 6;

    __shared__ int sidx[K_MAX];
    if (tid < K_MAX) sidx[tid] = idx[s * K_MAX + tid];
    __syncthreads();

    const int cnt   = counts[s];
    const int trial = trials[s];
    const float* base = spikes + (size_t)trial * T_MS * N_NEURONS;

    for (int tt = wave; tt < 100; tt += 4) {
        const int t = t_base + tt;
        const float* row = base + (size_t)t * N_NEURONS;
        float acc = 0.f;
        for (int k = lane; k < cnt; k += 64) {
            acc += row[sidx[k]];
        }
        #pragma unroll
        for (int off = 32; off > 0; off >>= 1)
            acc += __shfl_down(acc, off, 64);
        if (lane == 0) sel[s * T_MS + t] = acc;
    }
}

// Kernel 2: per (sample, bin-size) -> var/max(mean,eps). Two-pass for accuracy.
__global__ __launch_bounds__(256) void fano_kernel(
    const float* __restrict__ sel,
    float*       __restrict__ term)
{
    const int s   = blockIdx.x;
    const int b   = blockIdx.y;
    const int bs  = BIN_SIZES[b];
    const int nb  = T_MS / bs;
    const int tid = threadIdx.x;
    const float* srow = sel + s * T_MS;

    __shared__ float red[256];
    __shared__ float s_mean;

    // Pass 1: mean of per-bin counts
    float psum = 0.f;
    for (int j = tid; j < nb; j += 256) {
        const float* p = srow + j * bs;
        float c = 0.f;
        for (int u = 0; u < bs; ++u) c += p[u];
        psum += c;
    }
    red[tid] = psum;
    __syncthreads();
    for (int off = 128; off > 0; off >>= 1) {
        if (tid < off) red[tid] += red[tid + off];
        __syncthreads();
    }
    if (tid == 0) s_mean = red[0] / (float)nb;
    __syncthreads();
    const float mean = s_mean;

    // Pass 2: population variance about actual mean
    float pvar = 0.f;
    for (int j = tid; j < nb; j += 256) {
        const float* p = srow + j * bs;
        float c = 0.f;
        for (int u = 0; u < bs; ++u) c += p[u];
        const float d = c - mean;
        pvar += d * d;
    }
    red[tid] = pvar;
    __syncthreads();
    for (int off = 128; off > 0; off >>= 1) {
        if (tid < off) red[tid] += red[tid + off];
        __syncthreads();
    }
    if (tid == 0) {
        const float var = red[0] / (float)nb;
        const float m = mean > EPS_F ? mean : EPS_F;
        term[b * N_SAMPLES + s] = var / m;
    }
}

// Kernel 3: fanos[b] = mean_s term[b][s]; out = 10 * mean_b (exp - fano)^2
__global__ void loss_kernel(
    const float* __restrict__ term,
    const float* __restrict__ exp_fanos,
    float*       __restrict__ out)
{
    const int tid = threadIdx.x;  // 64 threads
    __shared__ float sq[N_BINS];
    if (tid < N_BINS) {
        float sum = 0.f;
        for (int s = 0; s < N_SAMPLES; ++s) sum += term[tid * N_SAMPLES + s];
        const float fano = sum / (float)N_SAMPLES;
        const float d = exp_fanos[tid] - fano;
        sq[tid] = d * d;
    }
    __syncthreads();
    if (tid == 0) {
        float tot = 0.f;
        for (int b = 0; b < N_BINS; ++b) tot += sq[b];
        out[0] = SYNC_COST * tot / (float)N_BINS;
    }
}

extern "C" void kernel_launch(void* const* d_in, const int* in_sizes, int n_in,
                              void* d_out, int out_size, void* d_ws, size_t ws_size,
                              hipStream_t stream)
{
    const float* spikes    = (const float*)d_in[0];
    const float* exp_fanos = (const float*)d_in[1];
    const int*   trials    = (const int*)d_in[2];
    const int*   idx       = (const int*)d_in[3];
    const int*   counts    = (const int*)d_in[4];
    float*       out       = (float*)d_out;

    float* sel  = (float*)d_ws;               // 50*2500 floats = 500 KB
    float* term = sel + N_SAMPLES * T_MS;     // 20*50 floats = 4 KB

    sel_kernel<<<dim3(N_SAMPLES, 25), 256, 0, stream>>>(spikes, trials, idx, counts, sel);
    fano_kernel<<<dim3(N_SAMPLES, N_BINS), 256, 0, stream>>>(sel, term);
    loss_kernel<<<1, 64, 0, stream>>>(term, exp_fanos, out);
}

// Round 2
// 1634.356 us; speedup vs baseline: 1.0111x; 1.0111x over previous
//
#include <hip/hip_runtime.h>

#define N_TRIALS  8
#define T_MS      2500
#define N_NEURONS 16000
#define N_SAMPLES 50
#define K_MAX     160
#define N_BINS    20
#define SYNC_COST 10.0f
#define EPS_F     1e-7f
#define T_CHUNK   20

// np.round(np.logspace(-3, 0, 20) * 1000)
__device__ const int BIN_SIZES[N_BINS] = {1, 1, 2, 3, 4, 6, 9, 13, 18, 26,
                                          38, 55, 78, 113, 162, 234, 336, 483, 695, 1000};

// Kernel 0: build trial -> sample-list map (tiny).
__global__ void prep_kernel(const int* __restrict__ trials,
                            int* __restrict__ tm_ns,
                            int* __restrict__ tm_samp)
{
    const int tr = threadIdx.x;
    if (tr < N_TRIALS) {
        int n = 0;
        for (int s = 0; s < N_SAMPLES; ++s)
            if (trials[s] == tr) tm_samp[tr * N_SAMPLES + n++] = s;
        tm_ns[tr] = n;
    }
}

// Kernel 1: trial-grouped gather. One block per (trial, 20-t chunk); each
// (trial,t) row is touched by exactly ONE block -> guaranteed line dedup
// across all samples sharing the trial (union ~437 idx -> ~280 x 128B lines).
__global__ __launch_bounds__(256) void sel_kernel(
    const float* __restrict__ spikes,
    const int*   __restrict__ idx,
    const int*   __restrict__ counts,
    const int*   __restrict__ tm_ns,
    const int*   __restrict__ tm_samp,
    float*       __restrict__ sel)
{
    const int tr   = blockIdx.y;
    const int t0   = blockIdx.x * T_CHUNK;
    const int tid  = threadIdx.x;
    const int lane = tid & 63;
    const int wave = tid >> 6;

    __shared__ int s_ns;
    __shared__ int s_sid[N_SAMPLES];
    __shared__ int s_cnt[N_SAMPLES];
    __shared__ int s_off[N_SAMPLES + 1];
    __shared__ int s_cols[N_SAMPLES * K_MAX];   // 32 KB worst case

    if (tid == 0) s_ns = tm_ns[tr];
    __syncthreads();
    const int ns = s_ns;
    if (ns == 0) return;   // uniform across block

    if (tid < ns) {
        const int sid = tm_samp[tr * N_SAMPLES + tid];
        s_sid[tid] = sid;
        s_cnt[tid] = counts[sid];
    }
    __syncthreads();
    if (tid == 0) {
        int off = 0;
        for (int j = 0; j < ns; ++j) { s_off[j] = off; off += s_cnt[j]; }
        s_off[ns] = off;
    }
    __syncthreads();
    for (int j = 0; j < ns; ++j) {
        const int cnt = s_cnt[j], sid = s_sid[j], off = s_off[j];
        for (int k = tid; k < cnt; k += 256)
            s_cols[off + k] = idx[sid * K_MAX + k];
    }
    __syncthreads();

    const float* tb = spikes + (size_t)tr * T_MS * N_NEURONS;
    for (int tt = wave; tt < T_CHUNK; tt += 4) {
        const int t = t0 + tt;
        const float* row = tb + (size_t)t * N_NEURONS;
        for (int j = 0; j < ns; ++j) {
            const int cnt = s_cnt[j], off = s_off[j];
            float acc = 0.f;
            for (int k = lane; k < cnt; k += 64)
                acc += row[s_cols[off + k]];
            #pragma unroll
            for (int o = 32; o > 0; o >>= 1)
                acc += __shfl_down(acc, o, 64);
            if (lane == 0) sel[s_sid[j] * T_MS + t] = acc;
        }
    }
}

// Kernel 2: per (sample, bin-size) -> var/max(mean,eps). Two-pass.
__global__ __launch_bounds__(256) void fano_kernel(
    const float* __restrict__ sel,
    float*       __restrict__ term)
{
    const int s   = blockIdx.x;
    const int b   = blockIdx.y;
    const int bs  = BIN_SIZES[b];
    const int nb  = T_MS / bs;
    const int tid = threadIdx.x;
    const float* srow = sel + s * T_MS;

    __shared__ float red[256];
    __shared__ float s_mean;

    float psum = 0.f;
    for (int j = tid; j < nb; j += 256) {
        const float* p = srow + j * bs;
        float c = 0.f;
        for (int u = 0; u < bs; ++u) c += p[u];
        psum += c;
    }
    red[tid] = psum;
    __syncthreads();
    for (int off = 128; off > 0; off >>= 1) {
        if (tid < off) red[tid] += red[tid + off];
        __syncthreads();
    }
    if (tid == 0) s_mean = red[0] / (float)nb;
    __syncthreads();
    const float mean = s_mean;

    float pvar = 0.f;
    for (int j = tid; j < nb; j += 256) {
        const float* p = srow + j * bs;
        float c = 0.f;
        for (int u = 0; u < bs; ++u) c += p[u];
        const float d = c - mean;
        pvar += d * d;
    }
    red[tid] = pvar;
    __syncthreads();
    for (int off = 128; off > 0; off >>= 1) {
        if (tid < off) red[tid] += red[tid + off];
        __syncthreads();
    }
    if (tid == 0) {
        const float var = red[0] / (float)nb;
        const float m = mean > EPS_F ? mean : EPS_F;
        term[b * N_SAMPLES + s] = var / m;
    }
}

// Kernel 3: fanos[b] = mean_s term[b][s]; out = 10 * mean_b (exp - fano)^2
__global__ void loss_kernel(
    const float* __restrict__ term,
    const float* __restrict__ exp_fanos,
    float*       __restrict__ out)
{
    const int tid = threadIdx.x;  // 64
    __shared__ float sq[N_BINS];
    if (tid < N_BINS) {
        float sum = 0.f;
        for (int s = 0; s < N_SAMPLES; ++s) sum += term[tid * N_SAMPLES + s];
        const float fano = sum / (float)N_SAMPLES;
        const float d = exp_fanos[tid] - fano;
        sq[tid] = d * d;
    }
    __syncthreads();
    if (tid == 0) {
        float tot = 0.f;
        for (int b = 0; b < N_BINS; ++b) tot += sq[b];
        out[0] = SYNC_COST * tot / (float)N_BINS;
    }
}

extern "C" void kernel_launch(void* const* d_in, const int* in_sizes, int n_in,
                              void* d_out, int out_size, void* d_ws, size_t ws_size,
                              hipStream_t stream)
{
    const float* spikes    = (const float*)d_in[0];
    const float* exp_fanos = (const float*)d_in[1];
    const int*   trials    = (const int*)d_in[2];
    const int*   idx       = (const int*)d_in[3];
    const int*   counts    = (const int*)d_in[4];
    float*       out       = (float*)d_out;

    float* sel   = (float*)d_ws;                      // 125000 floats
    float* term  = sel + N_SAMPLES * T_MS;            // 1000 floats
    int*   tm_ns = (int*)(term + N_BINS * N_SAMPLES); // 8 ints
    int*   tm_sa = tm_ns + N_TRIALS;                  // 400 ints

    prep_kernel<<<1, 64, 0, stream>>>(trials, tm_ns, tm_sa);
    sel_kernel<<<dim3(T_MS / T_CHUNK, N_TRIALS), 256, 0, stream>>>(
        spikes, idx, counts, tm_ns, tm_sa, sel);
    fano_kernel<<<dim3(N_SAMPLES, N_BINS), 256, 0, stream>>>(sel, term);
    loss_kernel<<<1, 64, 0, stream>>>(term, exp_fanos, out);
}

// Round 3
// 1629.895 us; speedup vs baseline: 1.0139x; 1.0027x over previous
//
#include <hip/hip_runtime.h>

#define N_TRIALS  8
#define T_MS      2500
#define N_NEURONS 16000
#define N_SAMPLES 50
#define K_MAX     160
#define N_BINS    20
#define SYNC_COST 10.0f
#define EPS_F     1e-7f
#define T_CHUNK   20

// np.round(np.logspace(-3, 0, 20) * 1000)
__device__ const int BIN_SIZES[N_BINS] = {1, 1, 2, 3, 4, 6, 9, 13, 18, 26,
                                          38, 55, 78, 113, 162, 234, 336, 483, 695, 1000};

// Kernel 1: trial-grouped gather, prep fused in-block.
// One block per (trial, 20-t chunk); each (trial,t) row touched by exactly
// one block -> line dedup across samples sharing the trial.
__global__ __launch_bounds__(256) void sel_kernel(
    const float* __restrict__ spikes,
    const int*   __restrict__ trials,
    const int*   __restrict__ idx,
    const int*   __restrict__ counts,
    float*       __restrict__ sel)
{
    const int tr   = blockIdx.y;
    const int t0   = blockIdx.x * T_CHUNK;
    const int tid  = threadIdx.x;
    const int lane = tid & 63;
    const int wave = tid >> 6;

    __shared__ int s_tr[N_SAMPLES];
    __shared__ int s_ns;
    __shared__ int s_sid[N_SAMPLES];
    __shared__ int s_cnt[N_SAMPLES];
    __shared__ int s_off[N_SAMPLES + 1];
    __shared__ int s_cols[N_SAMPLES * K_MAX];   // 32 KB worst case

    if (tid < N_SAMPLES) s_tr[tid] = trials[tid];
    __syncthreads();
    if (tid == 0) {
        int n = 0;
        for (int s = 0; s < N_SAMPLES; ++s)
            if (s_tr[s] == tr) s_sid[n++] = s;
        s_ns = n;
    }
    __syncthreads();
    const int ns = s_ns;
    if (ns == 0) return;   // uniform across block

    if (tid < ns) s_cnt[tid] = counts[s_sid[tid]];
    __syncthreads();
    if (tid == 0) {
        int off = 0;
        for (int j = 0; j < ns; ++j) { s_off[j] = off; off += s_cnt[j]; }
        s_off[ns] = off;
    }
    __syncthreads();
    for (int j = 0; j < ns; ++j) {
        const int cnt = s_cnt[j], sid = s_sid[j], off = s_off[j];
        for (int k = tid; k < cnt; k += 256)
            s_cols[off + k] = idx[sid * K_MAX + k];
    }
    __syncthreads();

    const float* tb = spikes + (size_t)tr * T_MS * N_NEURONS;
    for (int tt = wave; tt < T_CHUNK; tt += 4) {
        const int t = t0 + tt;
        const float* row = tb + (size_t)t * N_NEURONS;
        for (int j = 0; j < ns; ++j) {
            const int cnt = s_cnt[j], off = s_off[j];
            float acc = 0.f;
            for (int k = lane; k < cnt; k += 64)
                acc += row[s_cols[off + k]];
            #pragma unroll
            for (int o = 32; o > 0; o >>= 1)
                acc += __shfl_down(acc, o, 64);
            if (lane == 0) sel[s_sid[j] * T_MS + t] = acc;
        }
    }
}

// Kernel 2: per (sample, bin-size) -> var/max(mean,eps). Two-pass.
__global__ __launch_bounds__(256) void fano_kernel(
    const float* __restrict__ sel,
    float*       __restrict__ term)
{
    const int s   = blockIdx.x;
    const int b   = blockIdx.y;
    const int bs  = BIN_SIZES[b];
    const int nb  = T_MS / bs;
    const int tid = threadIdx.x;
    const float* srow = sel + s * T_MS;

    __shared__ float red[256];
    __shared__ float s_mean;

    float psum = 0.f;
    for (int j = tid; j < nb; j += 256) {
        const float* p = srow + j * bs;
        float c = 0.f;
        for (int u = 0; u < bs; ++u) c += p[u];
        psum += c;
    }
    red[tid] = psum;
    __syncthreads();
    for (int off = 128; off > 0; off >>= 1) {
        if (tid < off) red[tid] += red[tid + off];
        __syncthreads();
    }
    if (tid == 0) s_mean = red[0] / (float)nb;
    __syncthreads();
    const float mean = s_mean;

    float pvar = 0.f;
    for (int j = tid; j < nb; j += 256) {
        const float* p = srow + j * bs;
        float c = 0.f;
        for (int u = 0; u < bs; ++u) c += p[u];
        const float d = c - mean;
        pvar += d * d;
    }
    red[tid] = pvar;
    __syncthreads();
    for (int off = 128; off > 0; off >>= 1) {
        if (tid < off) red[tid] += red[tid + off];
        __syncthreads();
    }
    if (tid == 0) {
        const float var = red[0] / (float)nb;
        const float m = mean > EPS_F ? mean : EPS_F;
        term[b * N_SAMPLES + s] = var / m;
    }
}

// Kernel 3: fanos[b] = mean_s term[b][s]; out = 10 * mean_b (exp - fano)^2
__global__ void loss_kernel(
    const float* __restrict__ term,
    const float* __restrict__ exp_fanos,
    float*       __restrict__ out)
{
    const int tid = threadIdx.x;  // 64
    __shared__ float sq[N_BINS];
    if (tid < N_BINS) {
        float sum = 0.f;
        for (int s = 0; s < N_SAMPLES; ++s) sum += term[tid * N_SAMPLES + s];
        const float fano = sum / (float)N_SAMPLES;
        const float d = exp_fanos[tid] - fano;
        sq[tid] = d * d;
    }
    __syncthreads();
    if (tid == 0) {
        float tot = 0.f;
        for (int b = 0; b < N_BINS; ++b) tot += sq[b];
        out[0] = SYNC_COST * tot / (float)N_BINS;
    }
}

extern "C" void kernel_launch(void* const* d_in, const int* in_sizes, int n_in,
                              void* d_out, int out_size, void* d_ws, size_t ws_size,
                              hipStream_t stream)
{
    const float* spikes    = (const float*)d_in[0];
    const float* exp_fanos = (const float*)d_in[1];
    const int*   trials    = (const int*)d_in[2];
    const int*   idx       = (const int*)d_in[3];
    const int*   counts    = (const int*)d_in[4];
    float*       out       = (float*)d_out;

    float* sel  = (float*)d_ws;               // 125000 floats
    float* term = sel + N_SAMPLES * T_MS;     // 1000 floats

    sel_kernel<<<dim3(T_MS / T_CHUNK, N_TRIALS), 256, 0, stream>>>(
        spikes, trials, idx, counts, sel);
    fano_kernel<<<dim3(N_SAMPLES, N_BINS), 256, 0, stream>>>(sel, term);
    loss_kernel<<<1, 64, 0, stream>>>(term, exp_fanos, out);
}